// Round 7
// baseline (832.000 us; speedup 1.0000x reference)
//
#include <hip/hip_runtime.h>
#include <stdint.h>

#define D_MODEL   1024
#define N_EXPERTS 8
#define D_HIDDEN  4096
#define T_TOKENS  8192
#define N_SLOTS   (T_TOKENS * 2)

typedef __bf16 bf16x8 __attribute__((ext_vector_type(8)));
typedef float  f32x4  __attribute__((ext_vector_type(4)));
typedef unsigned short ushort8 __attribute__((ext_vector_type(8)));

__device__ __forceinline__ unsigned short f2bf(float f) {
    unsigned int u = __float_as_uint(f);
    u += 0x7fffu + ((u >> 16) & 1u);   // round-to-nearest-even
    return (unsigned short)(u >> 16);
}
__device__ __forceinline__ float bf2f(unsigned short v) {
    return __uint_as_float((unsigned int)v << 16);
}

__device__ __forceinline__ void gl_lds16(const void* g, void* l) {
    __builtin_amdgcn_global_load_lds(
        (const __attribute__((address_space(1))) unsigned int*)g,
        (__attribute__((address_space(3))) unsigned int*)l, 16, 0, 0);
}

// ------- gating: logits -> top2 -> softmax -> counts; also converts x->bf16 -------
__global__ __launch_bounds__(256) void gate_kernel(
    const float* __restrict__ x, const float* __restrict__ gw,
    unsigned short* __restrict__ xb,
    int* __restrict__ route_pack, float* __restrict__ route_w,
    int* __restrict__ cnt)
{
    __shared__ float gws[N_EXPERTS * D_MODEL];
    __shared__ int hist[N_EXPERTS];
    int tid = threadIdx.x;
    for (int i = tid * 4; i < N_EXPERTS * D_MODEL; i += 256 * 4)
        *(float4*)&gws[i] = *(const float4*)&gw[i];
    if (tid < N_EXPERTS) hist[tid] = 0;
    __syncthreads();

    int wave = tid >> 6, lane = tid & 63;
    for (int tt = 0; tt < 4; tt++) {
        int t = blockIdx.x * 16 + wave * 4 + tt;
        const float* xr = x + (size_t)t * D_MODEL;

        float acc[N_EXPERTS];
        for (int e = 0; e < N_EXPERTS; e++) acc[e] = 0.f;
        for (int i = 0; i < 4; i++) {
            float4 xv = *(const float4*)&xr[lane * 4 + i * 256];
            ushort4 o;
            o.x = f2bf(xv.x); o.y = f2bf(xv.y); o.z = f2bf(xv.z); o.w = f2bf(xv.w);
            *(ushort4*)&xb[(size_t)t * D_MODEL + lane * 4 + i * 256] = o;
            for (int e = 0; e < N_EXPERTS; e++) {
                float4 gv = *(const float4*)&gws[e * D_MODEL + lane * 4 + i * 256];
                acc[e] += xv.x * gv.x + xv.y * gv.y + xv.z * gv.z + xv.w * gv.w;
            }
        }
        for (int e = 0; e < N_EXPERTS; e++)
            for (int off = 32; off >= 1; off >>= 1)
                acc[e] += __shfl_xor(acc[e], off, 64);

        if (lane == 0) {
            int e0 = 0; float v0 = acc[0];
            for (int e = 1; e < N_EXPERTS; e++) if (acc[e] > v0) { v0 = acc[e]; e0 = e; }
            int e1 = (e0 == 0) ? 1 : 0; float v1 = acc[e1];
            for (int e = 0; e < N_EXPERTS; e++)
                if (e != e0 && acc[e] > v1) { v1 = acc[e]; e1 = e; }
            float w0 = 1.f / (1.f + __expf(v1 - v0));
            route_pack[t] = e0 | (e1 << 8);
            route_w[2 * t]     = w0;
            route_w[2 * t + 1] = 1.f - w0;
            atomicAdd(&hist[e0], 1);
            atomicAdd(&hist[e1], 1);
        }
    }
    __syncthreads();
    if (tid < N_EXPERTS) atomicAdd(&cnt[tid], hist[tid]);
}

__global__ void offsets_kernel(const int* __restrict__ cnt,
                               int* __restrict__ off, int* __restrict__ cnt2)
{
    if (threadIdx.x == 0) {
        int a = 0;
        for (int e = 0; e < N_EXPERTS; e++) { off[e] = a; a += cnt[e]; cnt2[e] = 0; }
        off[N_EXPERTS] = a;
    }
}

// ------- scatter via wave ballot-ranking -------
__global__ __launch_bounds__(64) void scatter_kernel(
    const int* __restrict__ route_pack, const int* __restrict__ off,
    int* __restrict__ cnt2, int* __restrict__ tok_id, int* __restrict__ inv)
{
    int lane = threadIdx.x;
    int t = blockIdx.x * 64 + lane;
    int p  = route_pack[t];
    int e0 = p & 0xff, e1 = (p >> 8) & 0xff;

    unsigned long long m0[N_EXPERTS], m1[N_EXPERTS];
    for (int e = 0; e < N_EXPERTS; e++) {
        m0[e] = __ballot(e0 == e);
        m1[e] = __ballot(e1 == e);
    }
    int mybase = 0;
    if (lane < N_EXPERTS)
        mybase = atomicAdd(&cnt2[lane], __popcll(m0[lane]) + __popcll(m1[lane]));

    unsigned long long lt = (1ull << lane) - 1ull;
    int b0 = __shfl(mybase, e0);
    int s0 = off[e0] + b0 + (int)__popcll(m0[e0] & lt);
    int b1 = __shfl(mybase, e1);
    int s1 = off[e1] + b1 + (int)__popcll(m0[e1]) + (int)__popcll(m1[e1] & lt);

    tok_id[s0] = t;
    tok_id[s1] = t;
    inv[2 * t]     = s0;
    inv[2 * t + 1] = s1;
}

// src: [E][R][C] fp32  ->  dst: [E][C][R] bf16   (64x64 tiles, 16B-coalesced)
template <int R, int C>
__global__ __launch_bounds__(256) void transpose_convert_kernel(
    const float* __restrict__ src, unsigned short* __restrict__ dst)
{
    __shared__ float tile[64 * 68];
    int e = blockIdx.z;
    const float* s = src + (size_t)e * R * C;
    unsigned short* d = dst + (size_t)e * R * C;
    int r0 = blockIdx.y * 64, c0 = blockIdx.x * 64;
    int t = threadIdx.x;
    {
        int r = t >> 4, c4 = (t & 15) * 4;
        for (int p = 0; p < 4; p++, r += 16)
            *(float4*)&tile[r * 68 + c4] = *(const float4*)&s[(size_t)(r0 + r) * C + c0 + c4];
    }
    __syncthreads();
    {
        int c = t >> 2, rblk = (t & 3) * 8;
        for (int q = 0; q < 2; q++) {
            int rr = q * 32 + rblk;
            ushort8 o;
            for (int j = 0; j < 8; j++) o[j] = f2bf(tile[(rr + j) * 68 + c]);
            *(ushort8*)&d[(size_t)(c0 + c) * R + r0 + rr] = o;
        }
    }
}

// ======== grouped GEMM: 256x256, BK=64, 8-PHASE counted-vmcnt schedule ========
// 8 waves (2M x 4N); phase (hh,nn): all waves read A stripe {r: r&64==hh*64} and
// B stripe {r: r&32==nn*32} -> stripe-granular staging is WAR-safe:
//   A0 dead after ph1, B0 after ph2, A1/B1 after ph3 (same per buffer in ph4-7).
// Stage plan (1 half = 2 gl_lds/thread): ph0 A1(V)->b1, ph1 B1(V)->b1,
//   ph2 A0(U+2)->b0, ph3 B0(U+2)->b0 +vmcnt(4), ph4 A1(U+2)->b0, ph5 B1(U+2)->b0,
//   ph6 A0(V+2)->b1, ph7 B0(V+2)->b1 +vmcnt(4).  Never vmcnt(0) in the loop.
// FIFO check: at ph3-wait the 8 completed oldest = all 4 halves of V; at ph7-wait
// = all 4 halves of U+2. Remaining 4 loads = the 2 newest halves (in flight).
template<int KDIM, int NC, bool RELU, bool USE_TOK>
__global__ __launch_bounds__(512, 2) void moe_gemm_kernel(
    const unsigned short* __restrict__ Ag, const unsigned short* __restrict__ Bw,
    const float* __restrict__ bias, const int* __restrict__ tok_id,
    const int* __restrict__ off, unsigned short* __restrict__ Cout)
{
    constexpr int NT   = KDIM / 64;               // K-tiles (16 or 64, even)
    constexpr int NTN  = NC / 256;                // N-tiles
    constexpr int NWG  = (N_SLOTS / 256) * NTN;   // 1024 / 256, both %8==0
    constexpr int ASH  = 256 * 64;                // A shorts per buffer (32 KB)
    constexpr int BUFS = 2 * ASH;                 // A+B per buffer (64 KB)
    __shared__ unsigned short smem[2 * BUFS];     // 128 KB

    int wg = blockIdx.x;
    int sz = (wg & 7) * (NWG / 8) + (wg >> 3);    // T1 XCD swizzle (NWG%8==0)
    int bx = sz / NTN;
    int n0 = (sz % NTN) * 256;
    int m0 = bx * 256;

    int tid = threadIdx.x, wave = tid >> 6, lane = tid & 63;
    int wm = wave >> 2, wn = wave & 3;            // 2M x 4N
    int lr = lane >> 3, lc = lane & 7;
    int lcs = lc ^ lr;                            // T2 source-side chunk swizzle
    int row16 = lane & 15, qk = lane >> 4;
    int sx = row16 & 7;                           // T2 read-side chunk XOR

    // ---- staging pointers: half hh, call c -> 8 consecutive rows of the stripe ----
    const unsigned short* gA[2][2];
    const unsigned short* gB[2][2];
    int lbA[2][2], lbB[2][2];
    int rowA[2][2], rowB[2][2];
#pragma unroll
    for (int hh = 0; hh < 2; hh++)
#pragma unroll
        for (int c = 0; c < 2; c++) {
            int q = wave * 16 + c * 8;                         // wave-uniform base
            int ra = (q & 63) + ((q >> 6) << 7) + hh * 64;     // A stripe: r&64==hh*64
            int rb = (q & 31) + ((q >> 5) << 6) + hh * 32;     // B stripe: r&32==nn*32
            rowA[hh][c] = ra; rowB[hh][c] = rb;
            lbA[hh][c] = ra * 64;
            lbB[hh][c] = ASH + rb * 64;
            int grow;
            if constexpr (USE_TOK) grow = tok_id[m0 + ra + lr]; else grow = m0 + ra + lr;
            gA[hh][c] = Ag + (size_t)grow * KDIM + lcs * 8;
        }

    auto stA = [&](int b, int hh, int kt) {
        gl_lds16(gA[hh][0] + kt * 64, smem + b * BUFS + lbA[hh][0]);
        gl_lds16(gA[hh][1] + kt * 64, smem + b * BUFS + lbA[hh][1]);
    };
    auto stB = [&](int b, int nn, int kt) {
        gl_lds16(gB[nn][0] + kt * 64, smem + b * BUFS + lbB[nn][0]);
        gl_lds16(gB[nn][1] + kt * 64, smem + b * BUFS + lbB[nn][1]);
    };

#define PHASE(BB, HH, NN, STAGE, VM)                                              \
    do {                                                                          \
        const unsigned short* Ab_ = smem + (BB) * BUFS;                           \
        const unsigned short* Bb_ = Ab_ + ASH;                                    \
        bf16x8 af[4][2], bq[2][2];                                                \
        _Pragma("unroll") for (int ii = 0; ii < 4; ii++)                          \
        _Pragma("unroll") for (int ks = 0; ks < 2; ks++) {                        \
            int rr = wm * 128 + (HH) * 64 + ii * 16 + row16;                      \
            af[ii][ks] = *(const bf16x8*)&Ab_[rr * 64 + (((ks * 4 + qk) ^ sx) * 8)]; } \
        _Pragma("unroll") for (int j = 0; j < 2; j++)                             \
        _Pragma("unroll") for (int ks = 0; ks < 2; ks++) {                        \
            int br = wn * 64 + (NN) * 32 + j * 16 + row16;                        \
            bq[j][ks] = *(const bf16x8*)&Bb_[br * 64 + (((ks * 4 + qk) ^ sx) * 8)]; } \
        STAGE;                                                                    \
        __builtin_amdgcn_s_barrier();                                             \
        __builtin_amdgcn_s_setprio(1);                                            \
        _Pragma("unroll") for (int ks = 0; ks < 2; ks++)                          \
        _Pragma("unroll") for (int ii = 0; ii < 4; ii++)                          \
        _Pragma("unroll") for (int j = 0; j < 2; j++)                             \
            acc[(HH) * 4 + ii][(NN) * 2 + j] = __builtin_amdgcn_mfma_f32_16x16x32_bf16( \
                af[ii][ks], bq[j][ks], acc[(HH) * 4 + ii][(NN) * 2 + j], 0, 0, 0);\
        __builtin_amdgcn_s_setprio(0);                                            \
        if (VM) asm volatile("s_waitcnt vmcnt(4)" ::: "memory");                  \
        __builtin_amdgcn_s_barrier();                                             \
    } while (0)

    f32x4 acc[8][4];
    const f32x4 zero = {0.f, 0.f, 0.f, 0.f};

    // segment loop: block-uniform; boundary M-tiles rerun the K-loop per expert
    for (int e = 0; e < N_EXPERTS; e++) {
        int lo = off[e], hi = off[e + 1];
        if (lo < m0) lo = m0;
        if (hi > m0 + 256) hi = m0 + 256;
        if (lo >= hi) continue;

#pragma unroll
        for (int nn = 0; nn < 2; nn++)
#pragma unroll
            for (int c = 0; c < 2; c++)
                gB[nn][c] = Bw + ((size_t)e * NC + n0 + rowB[nn][c] + lr) * KDIM + lcs * 8;

#pragma unroll
        for (int i = 0; i < 8; i++)
#pragma unroll
            for (int j = 0; j < 4; j++) acc[i][j] = zero;

        __syncthreads();   // prior segment epilogue LDS traffic complete
        // prologue: tile 0 fully -> buf0; A0,B0 of tile 1 -> buf1 (stay in flight)
        stA(0, 0, 0); stB(0, 0, 0); stA(0, 1, 0); stB(0, 1, 0);
        stA(1, 0, 1); stB(1, 0, 1);
        asm volatile("s_waitcnt vmcnt(4)" ::: "memory");
        __builtin_amdgcn_s_barrier();

        for (int it = 0; it < NT / 2; it++) {
            int V  = 2 * it + 1;
            int U2 = (2 * it + 2 < NT) ? 2 * it + 2 : NT - 1;  // tail: garbage into dead regions
            int V2 = (2 * it + 3 < NT) ? 2 * it + 3 : NT - 1;
            PHASE(0, 0, 0, stA(1, 1, V),  false);
            PHASE(0, 0, 1, stB(1, 1, V),  false);
            PHASE(0, 1, 0, stA(0, 0, U2), false);
            PHASE(0, 1, 1, stB(0, 0, U2), true);
            PHASE(1, 0, 0, stA(0, 1, U2), false);
            PHASE(1, 0, 1, stB(0, 1, U2), false);
            PHASE(1, 1, 0, stA(1, 0, V2), false);
            PHASE(1, 1, 1, stB(1, 0, V2), true);
        }

        asm volatile("s_waitcnt vmcnt(0) lgkmcnt(0)" ::: "memory");
        __syncthreads();

        // epilogue: stage 128-row output halves in LDS, store rows in [lo,hi) only
        unsigned short* stg = smem;
        int quad = lane >> 4, c16 = lane & 15;
        for (int p = 0; p < 2; p++) {
            if (p) __syncthreads();
            if (wm == p) {
#pragma unroll
                for (int j = 0; j < 4; j++) {
                    int n = n0 + wn * 64 + j * 16 + c16;
                    float bv = bias[e * NC + n];
#pragma unroll
                    for (int i = 0; i < 8; i++)
#pragma unroll
                        for (int r = 0; r < 4; r++) {
                            float v = acc[i][j][r] + bv;
                            if (RELU) v = v > 0.f ? v : 0.f;
                            stg[(i * 16 + quad * 4 + r) * 264 + wn * 64 + j * 16 + c16] = f2bf(v);
                        }
                }
            }
            __syncthreads();
            int srow = tid >> 5, chunk = (tid & 31) * 8;
#pragma unroll
            for (int s8 = 0; s8 < 8; s8++) {
                int rr = srow + s8 * 16;
                int slot = m0 + p * 128 + rr;
                if (slot >= lo && slot < hi)
                    *(ushort8*)&Cout[(size_t)slot * NC + n0 + chunk] =
                        *(const ushort8*)&stg[rr * 264 + chunk];
            }
        }
    }
#undef PHASE
}

// -------- combine: out[t] = w0*y[s0] + w1*y[s1] --------
__global__ __launch_bounds__(256) void combine_kernel(
    const unsigned short* __restrict__ y, const int* __restrict__ inv,
    const float* __restrict__ rw, float* __restrict__ out)
{
    int wave = threadIdx.x >> 6, lane = threadIdx.x & 63;
    int t = blockIdx.x * 4 + wave;
    int s0 = inv[2 * t], s1 = inv[2 * t + 1];
    float w0 = rw[2 * t], w1 = rw[2 * t + 1];
    const unsigned short* y0 = y + (size_t)s0 * D_MODEL;
    const unsigned short* y1 = y + (size_t)s1 * D_MODEL;
    float* orow = out + (size_t)t * D_MODEL;
    int c = lane * 16;
    for (int hh = 0; hh < 2; hh++) {
        ushort8 a = *(const ushort8*)&y0[c + hh * 8];
        ushort8 b = *(const ushort8*)&y1[c + hh * 8];
        float4 o0, o1;
        o0.x = w0 * bf2f(a[0]) + w1 * bf2f(b[0]);
        o0.y = w0 * bf2f(a[1]) + w1 * bf2f(b[1]);
        o0.z = w0 * bf2f(a[2]) + w1 * bf2f(b[2]);
        o0.w = w0 * bf2f(a[3]) + w1 * bf2f(b[3]);
        o1.x = w0 * bf2f(a[4]) + w1 * bf2f(b[4]);
        o1.y = w0 * bf2f(a[5]) + w1 * bf2f(b[5]);
        o1.z = w0 * bf2f(a[6]) + w1 * bf2f(b[6]);
        o1.w = w0 * bf2f(a[7]) + w1 * bf2f(b[7]);
        *(float4*)&orow[c + hh * 8]     = o0;
        *(float4*)&orow[c + hh * 8 + 4] = o1;
    }
}

// ---------------- launch ----------------
extern "C" void kernel_launch(void* const* d_in, const int* in_sizes, int n_in,
                              void* d_out, int out_size, void* d_ws, size_t ws_size,
                              hipStream_t stream)
{
    const float* x      = (const float*)d_in[0];
    const float* gate_w = (const float*)d_in[1];
    const float* w1     = (const float*)d_in[2];
    const float* b1     = (const float*)d_in[3];
    const float* w2     = (const float*)d_in[4];
    const float* b2     = (const float*)d_in[5];
    float* out = (float*)d_out;

    char* ws = (char*)d_ws;
    size_t o = 0;
    auto alloc = [&](size_t bytes) { void* p = ws + o; o += (bytes + 255) & ~(size_t)255; return p; };
    int*   cnt        = (int*)alloc(32);
    int*   cnt2       = (int*)alloc(32);
    int*   off        = (int*)alloc(64);
    int*   route_pack = (int*)alloc((size_t)T_TOKENS * 4);
    float* route_w    = (float*)alloc((size_t)T_TOKENS * 8);
    int*   tok_id     = (int*)alloc((size_t)N_SLOTS * 4);
    int*   inv        = (int*)alloc((size_t)T_TOKENS * 8);
    unsigned short* xb  = (unsigned short*)alloc((size_t)T_TOKENS * D_MODEL * 2);
    unsigned short* w1t = (unsigned short*)alloc((size_t)N_EXPERTS * D_MODEL * D_HIDDEN * 2);
    unsigned short* w2t = (unsigned short*)alloc((size_t)N_EXPERTS * D_MODEL * D_HIDDEN * 2);
    unsigned short* h   = (unsigned short*)alloc((size_t)N_SLOTS * D_HIDDEN * 2);
    // y aliases w1t (dead after gemm1)
    unsigned short* y   = w1t;

    hipMemsetAsync(cnt, 0, 32, stream);

    gate_kernel<<<T_TOKENS / 16, 256, 0, stream>>>(x, gate_w, xb, route_pack, route_w, cnt);
    offsets_kernel<<<1, 64, 0, stream>>>(cnt, off, cnt2);
    scatter_kernel<<<T_TOKENS / 64, 64, 0, stream>>>(route_pack, off, cnt2, tok_id, inv);
    transpose_convert_kernel<D_MODEL, D_HIDDEN>
        <<<dim3(D_HIDDEN / 64, D_MODEL / 64, N_EXPERTS), dim3(256), 0, stream>>>(w1, w1t);
    transpose_convert_kernel<D_HIDDEN, D_MODEL>
        <<<dim3(D_MODEL / 64, D_HIDDEN / 64, N_EXPERTS), dim3(256), 0, stream>>>(w2, w2t);
    moe_gemm_kernel<D_MODEL, D_HIDDEN, true, true>
        <<<dim3((N_SLOTS / 256) * (D_HIDDEN / 256)), dim3(512), 0, stream>>>(xb, w1t, b1, tok_id, off, h);
    moe_gemm_kernel<D_HIDDEN, D_MODEL, false, false>
        <<<dim3((N_SLOTS / 256) * (D_MODEL / 256)), dim3(512), 0, stream>>>(h, w2t, b2, tok_id, off, y);
    combine_kernel<<<T_TOKENS / 4, 256, 0, stream>>>(y, inv, route_w, out);
}

// Round 8
// 728.503 us; speedup vs baseline: 1.1421x; 1.1421x over previous
//
#include <hip/hip_runtime.h>
#include <stdint.h>

#define D_MODEL   1024
#define N_EXPERTS 8
#define D_HIDDEN  4096
#define T_TOKENS  8192
#define N_SLOTS   (T_TOKENS * 2)
#define MAX_MT    71    // sum_e ceil(n_e/256) <= 16384/256 + 7 = 71

typedef __bf16 bf16x8 __attribute__((ext_vector_type(8)));
typedef float  f32x4  __attribute__((ext_vector_type(4)));
typedef unsigned short ushort8 __attribute__((ext_vector_type(8)));

__device__ __forceinline__ unsigned short f2bf(float f) {
    unsigned int u = __float_as_uint(f);
    u += 0x7fffu + ((u >> 16) & 1u);   // round-to-nearest-even
    return (unsigned short)(u >> 16);
}
__device__ __forceinline__ float bf2f(unsigned short v) {
    return __uint_as_float((unsigned int)v << 16);
}

__device__ __forceinline__ void gl_lds16(const void* g, void* l) {
    __builtin_amdgcn_global_load_lds(
        (const __attribute__((address_space(1))) unsigned int*)g,
        (__attribute__((address_space(3))) unsigned int*)l, 16, 0, 0);
}

// ------- gating: logits -> top2 -> softmax -> counts; also converts x->bf16 -------
__global__ __launch_bounds__(256) void gate_kernel(
    const float* __restrict__ x, const float* __restrict__ gw,
    unsigned short* __restrict__ xb,
    int* __restrict__ route_pack, float* __restrict__ route_w,
    int* __restrict__ cnt)
{
    __shared__ float gws[N_EXPERTS * D_MODEL];
    __shared__ int hist[N_EXPERTS];
    int tid = threadIdx.x;
    for (int i = tid * 4; i < N_EXPERTS * D_MODEL; i += 256 * 4)
        *(float4*)&gws[i] = *(const float4*)&gw[i];
    if (tid < N_EXPERTS) hist[tid] = 0;
    __syncthreads();

    int wave = tid >> 6, lane = tid & 63;
    for (int tt = 0; tt < 4; tt++) {
        int t = blockIdx.x * 16 + wave * 4 + tt;
        const float* xr = x + (size_t)t * D_MODEL;

        float acc[N_EXPERTS];
        for (int e = 0; e < N_EXPERTS; e++) acc[e] = 0.f;
        for (int i = 0; i < 4; i++) {
            float4 xv = *(const float4*)&xr[lane * 4 + i * 256];
            ushort4 o;
            o.x = f2bf(xv.x); o.y = f2bf(xv.y); o.z = f2bf(xv.z); o.w = f2bf(xv.w);
            *(ushort4*)&xb[(size_t)t * D_MODEL + lane * 4 + i * 256] = o;
            for (int e = 0; e < N_EXPERTS; e++) {
                float4 gv = *(const float4*)&gws[e * D_MODEL + lane * 4 + i * 256];
                acc[e] += xv.x * gv.x + xv.y * gv.y + xv.z * gv.z + xv.w * gv.w;
            }
        }
        for (int e = 0; e < N_EXPERTS; e++)
            for (int off = 32; off >= 1; off >>= 1)
                acc[e] += __shfl_xor(acc[e], off, 64);

        if (lane == 0) {
            int e0 = 0; float v0 = acc[0];
            for (int e = 1; e < N_EXPERTS; e++) if (acc[e] > v0) { v0 = acc[e]; e0 = e; }
            int e1 = (e0 == 0) ? 1 : 0; float v1 = acc[e1];
            for (int e = 0; e < N_EXPERTS; e++)
                if (e != e0 && acc[e] > v1) { v1 = acc[e]; e1 = e; }
            float w0 = 1.f / (1.f + __expf(v1 - v0));
            route_pack[t] = e0 | (e1 << 8);
            route_w[2 * t]     = w0;
            route_w[2 * t + 1] = 1.f - w0;
            atomicAdd(&hist[e0], 1);
            atomicAdd(&hist[e1], 1);
        }
    }
    __syncthreads();
    if (tid < N_EXPERTS) atomicAdd(&cnt[tid], hist[tid]);
}

__global__ void offsets_kernel(const int* __restrict__ cnt,
                               int* __restrict__ off, int* __restrict__ cnt2)
{
    if (threadIdx.x == 0) {
        int a = 0;
        for (int e = 0; e < N_EXPERTS; e++) { off[e] = a; a += cnt[e]; cnt2[e] = 0; }
        off[N_EXPERTS] = a;
    }
}

// ------- scatter via wave ballot-ranking -------
__global__ __launch_bounds__(64) void scatter_kernel(
    const int* __restrict__ route_pack, const int* __restrict__ off,
    int* __restrict__ cnt2, int* __restrict__ tok_id, int* __restrict__ inv)
{
    int lane = threadIdx.x;
    int t = blockIdx.x * 64 + lane;
    int p  = route_pack[t];
    int e0 = p & 0xff, e1 = (p >> 8) & 0xff;

    unsigned long long m0[N_EXPERTS], m1[N_EXPERTS];
    for (int e = 0; e < N_EXPERTS; e++) {
        m0[e] = __ballot(e0 == e);
        m1[e] = __ballot(e1 == e);
    }
    int mybase = 0;
    if (lane < N_EXPERTS)
        mybase = atomicAdd(&cnt2[lane], __popcll(m0[lane]) + __popcll(m1[lane]));

    unsigned long long lt = (1ull << lane) - 1ull;
    int b0 = __shfl(mybase, e0);
    int s0 = off[e0] + b0 + (int)__popcll(m0[e0] & lt);
    int b1 = __shfl(mybase, e1);
    int s1 = off[e1] + b1 + (int)__popcll(m0[e1]) + (int)__popcll(m1[e1] & lt);

    tok_id[s0] = t;
    tok_id[s1] = t;
    inv[2 * t]     = s0;
    inv[2 * t + 1] = s1;
}

// src: [E][R][C] fp32  ->  dst: [E][C][R] bf16   (64x64 tiles, 16B-coalesced)
template <int R, int C>
__global__ __launch_bounds__(256) void transpose_convert_kernel(
    const float* __restrict__ src, unsigned short* __restrict__ dst)
{
    __shared__ float tile[64 * 68];
    int e = blockIdx.z;
    const float* s = src + (size_t)e * R * C;
    unsigned short* d = dst + (size_t)e * R * C;
    int r0 = blockIdx.y * 64, c0 = blockIdx.x * 64;
    int t = threadIdx.x;
    {
        int r = t >> 4, c4 = (t & 15) * 4;
        for (int p = 0; p < 4; p++, r += 16)
            *(float4*)&tile[r * 68 + c4] = *(const float4*)&s[(size_t)(r0 + r) * C + c0 + c4];
    }
    __syncthreads();
    {
        int c = t >> 2, rblk = (t & 3) * 8;
        for (int q = 0; q < 2; q++) {
            int rr = q * 32 + rblk;
            ushort8 o;
            for (int j = 0; j < 8; j++) o[j] = f2bf(tile[(rr + j) * 68 + c]);
            *(ushort8*)&d[(size_t)(c0 + c) * R + r0 + rr] = o;
        }
    }
}

// ======== grouped GEMM: 256x256, BK=64, 8-phase, corrected derived-waits ========
// 8 waves (2M x 4N). Phase (hh,nn): reads A stripe {r: r&64==hh*64} (persist af
// across the nn-pair -> A read once per hh) and B stripe {r: r&32==nn*32}.
// Region deaths (buf under consumption, phases p0..p3 of that buf):
//   A0 dead after p0's reads (af persisted in regs), B0 after p2, A1 after p2, B1 after p3.
// Stage plan (per iter; U=2it->buf0, V=2it+1->buf1, U2/V2 = +2 clamped):
//   ph0:{A1,B1}(V)->b1 [4]  ph2:A0(U2)->b0 [2]  ph3:B0(U2)->b0 [2]
//   ph4:{A1,B1}(U2)->b0 [4] ph6:A0(V2)->b1 [2]  ph7:B0(V2)->b1 [2]
// Waits: vmcnt(4) at end of ph3 (completes prev-ph6,prev-ph7,ph0 = all of V) and
// ph7 (completes ph2,ph3,ph4 = all of U2). Min issue->wait distance = 3 phases.
template<int KDIM, int NC, bool RELU, bool USE_TOK>
__global__ __launch_bounds__(512, 2) void moe_gemm_kernel(
    const unsigned short* __restrict__ Ag, const unsigned short* __restrict__ Bw,
    const float* __restrict__ bias, const int* __restrict__ tok_id,
    const int* __restrict__ off, unsigned short* __restrict__ Cout)
{
    constexpr int NT   = KDIM / 64;               // K-tiles (16 or 64, even)
    constexpr int NTN  = NC / 256;                // N-tiles
    constexpr int NWG  = MAX_MT * NTN;
    constexpr int ASH  = 256 * 64;                // A shorts per buffer (32 KB)
    constexpr int BUFS = 2 * ASH;                 // A+B per buffer (64 KB)
    __shared__ unsigned short smem[2 * BUFS];     // 128 KB

    // T1: bijective XCD swizzle (m204 formula, any NWG)
    int wg = blockIdx.x;
    constexpr int qq8 = NWG / 8, rr8 = NWG % 8;
    int xcd = wg & 7, idx = wg >> 3;
    int sz = (xcd < rr8 ? xcd * (qq8 + 1) : rr8 * (qq8 + 1) + (xcd - rr8) * qq8) + idx;
    int bx = sz / NTN;
    int n0 = (sz % NTN) * 256;

    int e = -1, slot0 = 0, end = 0;
    {
        int acc = 0;
        for (int i = 0; i < N_EXPERTS; i++) {
            int s = off[i], en = off[i + 1];
            int nt = (en - s + 255) >> 8;
            if (e < 0 && bx < acc + nt) { e = i; slot0 = s + (bx - acc) * 256; end = en; }
            acc += nt;
        }
        if (e < 0) return;
    }

    int tid = threadIdx.x, wave = tid >> 6, lane = tid & 63;
    int wm = wave >> 2, wn = wave & 3;            // 2M x 4N
    int lr = lane >> 3, lc = lane & 7;
    int lcs = lc ^ lr;                            // T2 source-side chunk swizzle
    int row16 = lane & 15, qk = lane >> 4;
    int sx = row16 & 7;                           // T2 read-side chunk XOR

    // ---- staging pointers: stripe half hh/nn, call c -> 8 rows of the stripe ----
    const unsigned short* gA[2][2];
    const unsigned short* gB[2][2];
    int lbA[2][2], lbB[2][2];
    int rowB[2][2];
#pragma unroll
    for (int hh = 0; hh < 2; hh++)
#pragma unroll
        for (int c = 0; c < 2; c++) {
            int q = wave * 16 + c * 8;                         // wave-uniform base
            int ra = (q & 63) + ((q >> 6) << 7) + hh * 64;     // A stripe: r&64==hh*64
            int rb = (q & 31) + ((q >> 5) << 6) + hh * 32;     // B stripe: r&32==nn*32
            rowB[hh][c] = rb;
            lbA[hh][c] = ra * 64;
            lbB[hh][c] = ASH + rb * 64;
            int slotc = min(slot0 + ra + lr, end - 1);
            int grow;
            if constexpr (USE_TOK) grow = tok_id[slotc]; else grow = slotc;
            gA[hh][c] = Ag + (size_t)grow * KDIM + lcs * 8;
            gB[hh][c] = Bw + ((size_t)e * NC + n0 + rb + lr) * KDIM + lcs * 8;
        }

    auto stA = [&](int b, int hh, int kt) {
        gl_lds16(gA[hh][0] + kt * 64, smem + b * BUFS + lbA[hh][0]);
        gl_lds16(gA[hh][1] + kt * 64, smem + b * BUFS + lbA[hh][1]);
    };
    auto stB = [&](int b, int nn, int kt) {
        gl_lds16(gB[nn][0] + kt * 64, smem + b * BUFS + lbB[nn][0]);
        gl_lds16(gB[nn][1] + kt * 64, smem + b * BUFS + lbB[nn][1]);
    };

    f32x4 acc[8][4];
    const f32x4 zero = {0.f, 0.f, 0.f, 0.f};
#pragma unroll
    for (int i = 0; i < 8; i++)
#pragma unroll
        for (int j = 0; j < 4; j++) acc[i][j] = zero;

#define READ_A(AB, HH)                                                            \
    _Pragma("unroll") for (int ii = 0; ii < 4; ii++)                              \
    _Pragma("unroll") for (int ks = 0; ks < 2; ks++)                              \
        af[ii][ks] = *(const bf16x8*)&(AB)[(wm * 128 + (HH) * 64 + ii * 16 + row16) * 64 \
                                           + (((ks * 4 + qk) ^ sx) * 8)];
#define READ_B(BB, NN)                                                            \
    _Pragma("unroll") for (int jj = 0; jj < 2; jj++)                              \
    _Pragma("unroll") for (int ks = 0; ks < 2; ks++)                              \
        bq[jj][ks] = *(const bf16x8*)&(BB)[(wn * 64 + (NN) * 32 + jj * 16 + row16) * 64 \
                                           + (((ks * 4 + qk) ^ sx) * 8)];
#define MFMA16(HH, NN)                                                            \
    __builtin_amdgcn_s_setprio(1);                                                \
    _Pragma("unroll") for (int ks = 0; ks < 2; ks++)                              \
    _Pragma("unroll") for (int ii = 0; ii < 4; ii++)                              \
    _Pragma("unroll") for (int jj = 0; jj < 2; jj++)                              \
        acc[(HH) * 4 + ii][(NN) * 2 + jj] = __builtin_amdgcn_mfma_f32_16x16x32_bf16( \
            af[ii][ks], bq[jj][ks], acc[(HH) * 4 + ii][(NN) * 2 + jj], 0, 0, 0);  \
    __builtin_amdgcn_s_setprio(0);
#define BAR() __builtin_amdgcn_s_barrier()
#define VMC4() asm volatile("s_waitcnt vmcnt(4)" ::: "memory")

    const unsigned short* A0b = smem;
    const unsigned short* B0b = smem + ASH;
    const unsigned short* A1b = smem + BUFS;
    const unsigned short* B1b = A1b + ASH;

    // prologue: tile0 full -> buf0 (8 loads); A0,B0 of tile1 -> buf1 (4, in flight)
    stA(0, 0, 0); stB(0, 0, 0); stA(0, 1, 0); stB(0, 1, 0);
    stA(1, 0, 1); stB(1, 0, 1);
    VMC4();
    BAR();

    for (int it = 0; it < NT / 2; it++) {
        int V  = 2 * it + 1;
        int U2 = (2 * it + 2 < NT) ? 2 * it + 2 : NT - 1;
        int V2 = (2 * it + 3 < NT) ? 2 * it + 3 : NT - 1;
        bf16x8 af[4][2], bq[2][2];
        // ph0: buf0 (0,0)
        READ_A(A0b, 0); READ_B(B0b, 0);
        stA(1, 1, V); stB(1, 1, V);
        BAR(); MFMA16(0, 0); BAR();
        // ph1: buf0 (0,1) — af persists
        READ_B(B0b, 1);
        BAR(); MFMA16(0, 1); BAR();
        // ph2: buf0 (1,0)
        READ_A(A0b, 1); READ_B(B0b, 0);
        stA(0, 0, U2);
        BAR(); MFMA16(1, 0); BAR();
        // ph3: buf0 (1,1)
        READ_B(B0b, 1);
        stB(0, 0, U2);
        BAR(); MFMA16(1, 1); VMC4(); BAR();
        // ph4: buf1 (0,0)
        READ_A(A1b, 0); READ_B(B1b, 0);
        stA(0, 1, U2); stB(0, 1, U2);
        BAR(); MFMA16(0, 0); BAR();
        // ph5: buf1 (0,1)
        READ_B(B1b, 1);
        BAR(); MFMA16(0, 1); BAR();
        // ph6: buf1 (1,0)
        READ_A(A1b, 1); READ_B(B1b, 0);
        stA(1, 0, V2);
        BAR(); MFMA16(1, 0); BAR();
        // ph7: buf1 (1,1)
        READ_B(B1b, 1);
        stB(1, 0, V2);
        BAR(); MFMA16(1, 1); VMC4(); BAR();
    }

    asm volatile("s_waitcnt vmcnt(0) lgkmcnt(0)" ::: "memory");
    __syncthreads();

#undef READ_A
#undef READ_B
#undef MFMA16
#undef BAR
#undef VMC4

    // epilogue: stage 128-row output halves in LDS, masked 16B stores
    unsigned short* stg = smem;
    int quad = lane >> 4, c16 = lane & 15;
    for (int p = 0; p < 2; p++) {
        if (p) __syncthreads();
        if (wm == p) {
#pragma unroll
            for (int j = 0; j < 4; j++) {
                int n = n0 + wn * 64 + j * 16 + c16;
                float bv = bias[e * NC + n];
#pragma unroll
                for (int i = 0; i < 8; i++)
#pragma unroll
                    for (int r = 0; r < 4; r++) {
                        float v = acc[i][j][r] + bv;
                        if (RELU) v = v > 0.f ? v : 0.f;
                        stg[(i * 16 + quad * 4 + r) * 264 + wn * 64 + j * 16 + c16] = f2bf(v);
                    }
            }
        }
        __syncthreads();
        int srow = tid >> 5, chunk = (tid & 31) * 8;
#pragma unroll
        for (int s8 = 0; s8 < 8; s8++) {
            int rr = srow + s8 * 16;
            int slot = slot0 + p * 128 + rr;
            if (slot < end)
                *(ushort8*)&Cout[(size_t)slot * NC + n0 + chunk] =
                    *(const ushort8*)&stg[rr * 264 + chunk];
        }
    }
}

// -------- combine: out[t] = w0*y[s0] + w1*y[s1] --------
__global__ __launch_bounds__(256) void combine_kernel(
    const unsigned short* __restrict__ y, const int* __restrict__ inv,
    const float* __restrict__ rw, float* __restrict__ out)
{
    int wave = threadIdx.x >> 6, lane = threadIdx.x & 63;
    int t = blockIdx.x * 4 + wave;
    int s0 = inv[2 * t], s1 = inv[2 * t + 1];
    float w0 = rw[2 * t], w1 = rw[2 * t + 1];
    const unsigned short* y0 = y + (size_t)s0 * D_MODEL;
    const unsigned short* y1 = y + (size_t)s1 * D_MODEL;
    float* orow = out + (size_t)t * D_MODEL;
    int c = lane * 16;
    for (int hh = 0; hh < 2; hh++) {
        ushort8 a = *(const ushort8*)&y0[c + hh * 8];
        ushort8 b = *(const ushort8*)&y1[c + hh * 8];
        float4 o0, o1;
        o0.x = w0 * bf2f(a[0]) + w1 * bf2f(b[0]);
        o0.y = w0 * bf2f(a[1]) + w1 * bf2f(b[1]);
        o0.z = w0 * bf2f(a[2]) + w1 * bf2f(b[2]);
        o0.w = w0 * bf2f(a[3]) + w1 * bf2f(b[3]);
        o1.x = w0 * bf2f(a[4]) + w1 * bf2f(b[4]);
        o1.y = w0 * bf2f(a[5]) + w1 * bf2f(b[5]);
        o1.z = w0 * bf2f(a[6]) + w1 * bf2f(b[6]);
        o1.w = w0 * bf2f(a[7]) + w1 * bf2f(b[7]);
        *(float4*)&orow[c + hh * 8]     = o0;
        *(float4*)&orow[c + hh * 8 + 4] = o1;
    }
}

// ---------------- launch ----------------
extern "C" void kernel_launch(void* const* d_in, const int* in_sizes, int n_in,
                              void* d_out, int out_size, void* d_ws, size_t ws_size,
                              hipStream_t stream)
{
    const float* x      = (const float*)d_in[0];
    const float* gate_w = (const float*)d_in[1];
    const float* w1     = (const float*)d_in[2];
    const float* b1     = (const float*)d_in[3];
    const float* w2     = (const float*)d_in[4];
    const float* b2     = (const float*)d_in[5];
    float* out = (float*)d_out;

    char* ws = (char*)d_ws;
    size_t o = 0;
    auto alloc = [&](size_t bytes) { void* p = ws + o; o += (bytes + 255) & ~(size_t)255; return p; };
    int*   cnt        = (int*)alloc(32);
    int*   cnt2       = (int*)alloc(32);
    int*   off        = (int*)alloc(64);
    int*   route_pack = (int*)alloc((size_t)T_TOKENS * 4);
    float* route_w    = (float*)alloc((size_t)T_TOKENS * 8);
    int*   tok_id     = (int*)alloc((size_t)N_SLOTS * 4);
    int*   inv        = (int*)alloc((size_t)T_TOKENS * 8);
    unsigned short* xb  = (unsigned short*)alloc((size_t)T_TOKENS * D_MODEL * 2);
    unsigned short* w1t = (unsigned short*)alloc((size_t)N_EXPERTS * D_MODEL * D_HIDDEN * 2);
    unsigned short* w2t = (unsigned short*)alloc((size_t)N_EXPERTS * D_MODEL * D_HIDDEN * 2);
    unsigned short* h   = (unsigned short*)alloc((size_t)N_SLOTS * D_HIDDEN * 2);
    // y aliases w1t (dead after gemm1)
    unsigned short* y   = w1t;

    hipMemsetAsync(cnt, 0, 32, stream);

    gate_kernel<<<T_TOKENS / 16, 256, 0, stream>>>(x, gate_w, xb, route_pack, route_w, cnt);
    offsets_kernel<<<1, 64, 0, stream>>>(cnt, off, cnt2);
    scatter_kernel<<<T_TOKENS / 64, 64, 0, stream>>>(route_pack, off, cnt2, tok_id, inv);
    transpose_convert_kernel<D_MODEL, D_HIDDEN>
        <<<dim3(D_HIDDEN / 64, D_MODEL / 64, N_EXPERTS), dim3(256), 0, stream>>>(w1, w1t);
    transpose_convert_kernel<D_HIDDEN, D_MODEL>
        <<<dim3(D_MODEL / 64, D_HIDDEN / 64, N_EXPERTS), dim3(256), 0, stream>>>(w2, w2t);
    moe_gemm_kernel<D_MODEL, D_HIDDEN, true, true>
        <<<dim3(MAX_MT * (D_HIDDEN / 256)), dim3(512), 0, stream>>>(xb, w1t, b1, tok_id, off, h);
    moe_gemm_kernel<D_HIDDEN, D_MODEL, false, false>
        <<<dim3(MAX_MT * (D_MODEL / 256)), dim3(512), 0, stream>>>(h, w2t, b2, tok_id, off, y);
    combine_kernel<<<T_TOKENS / 4, 256, 0, stream>>>(y, inv, route_w, out);
}